// Round 5
// baseline (192.451 us; speedup 1.0000x reference)
//
#include <hip/hip_runtime.h>
#include <hip/hip_bf16.h>
#include <math.h>

#define NB 16
#define NL 1000
#define NK 17
#define NC 17
#define NH 256
#define NW 256
#define HID 64
#define IN_DIM 51              // NK * (TOPK+1)
#define NPAIR (NB*NL)          // 16000
#define PADC 20                // featT row: 20 floats (80 B, 16B-aligned)
#define STATW 52               // stat row stride (208 B, 16B-aligned)
#define NSAMP (NPAIR*NK)       // 272000 samples
#define PPB_C 32               // pairs per MLP block (500 blocks exactly)
#define PPB_F 15               // fallback fused kernel pairs/block

typedef float f32x4 __attribute__((ext_vector_type(4)));

#define TOP2(v) do { const float _v = (v); \
    if (_v > m1) { m2 = m1; m1 = _v; } else if (_v > m2) { m2 = _v; } } while (0)

// ---------------- A: transpose feat[B,C,H,W] -> featT[B,H*W,PADC] --------------
__global__ __launch_bounds__(256) void transpose_feat(
    const float* __restrict__ feat, float* __restrict__ featT)
{
    __shared__ float s[NC][257];
    const int bid = blockIdx.x;                     // 4096 (div by 8)
    const int l   = ((bid & 7) << 9) | (bid >> 3);  // XCD x -> batches {2x,2x+1}
    const int b   = l >> 8;
    const int hw0 = (l & 255) << 8;
    const int tid = threadIdx.x;
    const float* fb = feat + (size_t)b * NC * (NH * NW) + hw0;
    #pragma unroll
    for (int c = 0; c < NC; ++c)
        s[c][tid] = fb[c * (NH * NW) + tid];
    __syncthreads();
    float4* outp = reinterpret_cast<float4*>(
        featT + ((size_t)b * (NH * NW) + hw0) * PADC);
    #pragma unroll
    for (int i = tid; i < 256 * PADC / 4; i += 256) {
        const int p = i / 5;
        const int j = i - 5 * p;
        float4 v;
        if (j < 4) {
            const int c = 4 * j;
            v = make_float4(s[c][p], s[c + 1][p], s[c + 2][p], s[c + 3][p]);
        } else {
            v = make_float4(s[16][p], 0.f, 0.f, 0.f);
        }
        outp[i] = v;
    }
}

// ---------------- B: corner-split gather, 4 lanes per sample -------------------
// Each lane loads one bilinear corner (5 independent loads, issued up-front,
// nontemporal to bypass L1), scales by its corner weight, then an exact-order
// shuffle combine reproduces (((w00*g0 + w10*g1) + w01*g2) + w11*g3) bit-for-bit.
__global__ __launch_bounds__(256) void sample_top2(
    const float* __restrict__ pred_poses,
    const float* __restrict__ featT,
    float* __restrict__ stat)
{
    const int t  = blockIdx.x * 256 + threadIdx.x;  // grid exact: NSAMP*4/256
    const int s  = t >> 2;                          // sample id
    const int cr = t & 3;                           // corner: 0=00 1=10 2=01 3=11
    const int pair = s / NK;
    const int k    = s - pair * NK;
    const int b    = pair / NL;

    const float2 p = *reinterpret_cast<const float2*>(
        pred_poses + (size_t)pair * (2 * NK) + 2 * k);
    const float gx = 2.0f * p.x - 1.0f;
    const float gy = 2.0f * p.y - 1.0f;
    const float fx = (gx + 1.0f) * (0.5f * NW) - 0.5f;
    const float fy = (gy + 1.0f) * (0.5f * NH) - 0.5f;
    const float x0f = floorf(fx), y0f = floorf(fy);
    const float wx = fx - x0f,   wy = fy - y0f;

    const int dx = cr & 1, dy = cr >> 1;
    const int ix = (int)x0f + dx;
    const int iy = (int)y0f + dy;
    const float fxw = dx ? wx : (1.f - wx);         // exact per-corner factors
    const float fyw = dy ? wy : (1.f - wy);
    const float vx  = (ix >= 0 && ix < NW) ? 1.f : 0.f;
    const float vy  = (iy >= 0 && iy < NH) ? 1.f : 0.f;
    const float wc  = fxw * fyw * vx * vy;
    const int cx = min(max(ix, 0), NW - 1);
    const int cy = min(max(iy, 0), NH - 1);
    const float* rp = featT + ((size_t)b * (NH * NW) + (size_t)(cy * NW + cx)) * PADC;

    // 5 independent loads, all in flight together
    const f32x4 r0 = __builtin_nontemporal_load((const f32x4*)(rp));
    const f32x4 r1 = __builtin_nontemporal_load((const f32x4*)(rp + 4));
    const f32x4 r2 = __builtin_nontemporal_load((const f32x4*)(rp + 8));
    const f32x4 r3 = __builtin_nontemporal_load((const f32x4*)(rp + 12));
    const float r4 = __builtin_nontemporal_load(rp + 16);

    float v[NC];
    #pragma unroll
    for (int j = 0; j < 4; ++j) {
        v[4 * j + 0] = wc * r0[0], v[4 * j + 1] = wc * r0[1],
        v[4 * j + 2] = wc * r0[2], v[4 * j + 3] = wc * r0[3];
    }
    v[0]  = wc * r0[0]; v[1]  = wc * r0[1]; v[2]  = wc * r0[2]; v[3]  = wc * r0[3];
    v[4]  = wc * r1[0]; v[5]  = wc * r1[1]; v[6]  = wc * r1[2]; v[7]  = wc * r1[3];
    v[8]  = wc * r2[0]; v[9]  = wc * r2[1]; v[10] = wc * r2[2]; v[11] = wc * r2[3];
    v[12] = wc * r3[0]; v[13] = wc * r3[1]; v[14] = wc * r3[2]; v[15] = wc * r3[3];
    v[16] = wc * r4;

    const int lane = threadIdx.x & 63;
    const int base = lane & ~3;
    float m1 = -INFINITY, m2 = -INFINITY;
    #pragma unroll
    for (int c = 0; c < NC; ++c) {
        const float t1 = __shfl(v[c], base + 1, 64);
        const float t2 = __shfl(v[c], base + 2, 64);
        const float t3 = __shfl(v[c], base + 3, 64);
        TOP2(((v[c] + t1) + t2) + t3);              // exact reference order
    }
    if (cr == 0) {
        float* sp = stat + (size_t)pair * STATW + 3 * k;
        sp[0] = m1;
        sp[1] = m2;
        sp[2] = 0.5f * (m1 + m2);
    }
}

// ---------------- C: tiny MLP 51->64->1 (round-4 verified, absmax 0) -----------
__global__ __launch_bounds__(256) void mlp_head(
    const float* __restrict__ scores,
    const float* __restrict__ stat,
    const float* __restrict__ w1,
    const float* __restrict__ b1,
    const float* __restrict__ w2,
    const float* __restrict__ b2,
    float* __restrict__ out)
{
    __shared__ float s_w1[HID * IN_DIM];
    __shared__ float s_b1[HID];
    __shared__ float s_w2[HID];
    const int tid = threadIdx.x;
    for (int i = tid; i < HID * IN_DIM; i += 256) s_w1[i] = w1[i];
    if (tid < HID) { s_b1[tid] = b1[tid]; s_w2[tid] = w2[tid]; }
    __syncthreads();

    const int lane = tid & 63;
    const int wv   = tid >> 6;
    float w1r[IN_DIM];
    #pragma unroll
    for (int i = 0; i < IN_DIM; ++i) w1r[i] = s_w1[lane * IN_DIM + i];
    const float hb  = s_b1[lane];
    const float hw  = s_w2[lane];
    const float vb2 = b2[0];

    const int p0 = blockIdx.x * PPB_C + wv * (PPB_C / 4);
    #pragma unroll
    for (int j = 0; j < PPB_C / 4; ++j) {
        const int pair = p0 + j;                    // wave-uniform
        const float* xp = stat + (size_t)pair * STATW;
        float h = hb;
        #pragma unroll
        for (int i = 0; i < IN_DIM; ++i)
            h = fmaf(xp[i], w1r[i], h);             // uniform -> scalar loads
        h = fmaxf(h, 0.f);
        float pval = h * hw;
        #pragma unroll
        for (int off = 32; off >= 1; off >>= 1)
            pval += __shfl_xor(pval, off, 64);
        if (lane == 0) out[pair] = scores[pair] + pval + vb2;
    }
}

// ---------------- fallback (round-1 verified): direct gather -------------------
__global__ __launch_bounds__(256) void lqe_fused_direct(
    const float* __restrict__ scores,
    const float* __restrict__ pred_poses,
    const float* __restrict__ feat,
    const float* __restrict__ w1,
    const float* __restrict__ b1,
    const float* __restrict__ w2,
    const float* __restrict__ b2,
    float* __restrict__ out)
{
    __shared__ float s_w1[HID * IN_DIM];
    __shared__ float s_b1[HID];
    __shared__ float s_w2[HID];
    __shared__ float s_x[PPB_F][IN_DIM + 1];

    const int tid = threadIdx.x;
    for (int i = tid; i < HID * IN_DIM; i += 256) s_w1[i] = w1[i];
    if (tid < HID) { s_b1[tid] = b1[tid]; s_w2[tid] = w2[tid]; }

    if (tid < PPB_F * NK) {
        const int lp = tid / NK;
        const int k  = tid - lp * NK;
        const int pair = blockIdx.x * PPB_F + lp;
        if (pair < NPAIR) {
            const int b = pair / NL;
            const float2 p = *reinterpret_cast<const float2*>(
                pred_poses + (size_t)pair * (2 * NK) + 2 * k);
            const float gx = 2.0f * p.x - 1.0f;
            const float gy = 2.0f * p.y - 1.0f;
            const float fx = (gx + 1.0f) * (0.5f * NW) - 0.5f;
            const float fy = (gy + 1.0f) * (0.5f * NH) - 0.5f;
            const float x0f = floorf(fx), y0f = floorf(fy);
            const float wx = fx - x0f,   wy = fy - y0f;
            const int ix0 = (int)x0f, iy0 = (int)y0f;
            const int ix1 = ix0 + 1,  iy1 = iy0 + 1;
            const float vx0 = (ix0 >= 0 && ix0 < NW) ? 1.f : 0.f;
            const float vx1 = (ix1 >= 0 && ix1 < NW) ? 1.f : 0.f;
            const float vy0 = (iy0 >= 0 && iy0 < NH) ? 1.f : 0.f;
            const float vy1 = (iy1 >= 0 && iy1 < NH) ? 1.f : 0.f;
            const float w00 = (1.f - wx) * (1.f - wy) * vx0 * vy0;
            const float w10 = wx * (1.f - wy) * vx1 * vy0;
            const float w01 = (1.f - wx) * wy * vx0 * vy1;
            const float w11 = wx * wy * vx1 * vy1;
            const int cx0 = min(max(ix0, 0), NW - 1), cx1 = min(max(ix1, 0), NW - 1);
            const int cy0 = min(max(iy0, 0), NH - 1), cy1 = min(max(iy1, 0), NH - 1);
            const int o00 = cy0 * NW + cx0, o10 = cy0 * NW + cx1;
            const int o01 = cy1 * NW + cx0, o11 = cy1 * NW + cx1;
            const float* fb = feat + (size_t)b * NC * NH * NW;
            float m1 = -INFINITY, m2 = -INFINITY;
            #pragma unroll
            for (int c = 0; c < NC; ++c) {
                const float* fc = fb + c * (NH * NW);
                TOP2(w00 * fc[o00] + w10 * fc[o10] + w01 * fc[o01] + w11 * fc[o11]);
            }
            s_x[lp][3 * k + 0] = m1;
            s_x[lp][3 * k + 1] = m2;
            s_x[lp][3 * k + 2] = 0.5f * (m1 + m2);
        }
    }
    __syncthreads();

    const int wv = tid >> 6;
    const int lane = tid & 63;
    const float vb2 = b2[0];
    for (int lp = wv; lp < PPB_F; lp += 4) {
        const int pair = blockIdx.x * PPB_F + lp;
        if (pair >= NPAIR) break;
        float h = s_b1[lane];
        #pragma unroll
        for (int i = 0; i < IN_DIM; ++i)
            h = fmaf(s_x[lp][i], s_w1[lane * IN_DIM + i], h);
        h = fmaxf(h, 0.f);
        float pval = h * s_w2[lane];
        #pragma unroll
        for (int off = 32; off >= 1; off >>= 1)
            pval += __shfl_xor(pval, off, 64);
        if (lane == 0) out[pair] = scores[pair] + pval + vb2;
    }
}

extern "C" void kernel_launch(void* const* d_in, const int* in_sizes, int n_in,
                              void* d_out, int out_size, void* d_ws, size_t ws_size,
                              hipStream_t stream) {
    const float* scores     = (const float*)d_in[0];
    const float* pred_poses = (const float*)d_in[1];
    const float* feat       = (const float*)d_in[2];
    const float* w1         = (const float*)d_in[3];
    const float* b1         = (const float*)d_in[4];
    const float* w2         = (const float*)d_in[5];
    const float* b2         = (const float*)d_in[6];
    float* out = (float*)d_out;

    const size_t bytesT = (size_t)NB * NH * NW * PADC * sizeof(float);  // 80 MB
    const size_t bytesS = (size_t)NPAIR * STATW * sizeof(float);        // 3.3 MB

    if (ws_size >= bytesT + bytesS) {
        float* featT = (float*)d_ws;
        float* stat  = (float*)((char*)d_ws + bytesT);
        transpose_feat<<<NB * 256, 256, 0, stream>>>(feat, featT);
        sample_top2<<<(NSAMP * 4) / 256, 256, 0, stream>>>(pred_poses, featT, stat);
        mlp_head<<<NPAIR / PPB_C, 256, 0, stream>>>(scores, stat,
                                                    w1, b1, w2, b2, out);
    } else {
        const int grid = (NPAIR + PPB_F - 1) / PPB_F;
        lqe_fused_direct<<<grid, 256, 0, stream>>>(scores, pred_poses, feat,
                                                   w1, b1, w2, b2, out);
    }
}

// Round 6
// 147.956 us; speedup vs baseline: 1.3007x; 1.3007x over previous
//
#include <hip/hip_runtime.h>
#include <hip/hip_bf16.h>
#include <math.h>

#define NB 16
#define NL 1000
#define NK 17
#define NC 17
#define NH 256
#define NW 256
#define HID 64
#define IN_DIM 51              // NK * (TOPK+1)
#define NPAIR (NB*NL)          // 16000
#define STATW 52               // stat row stride (208 B, 16B-aligned)
#define PPB 15                 // pairs per block in fused kernel
#define PAIRS_PER_XCD 2000     // 16000/8; = batches {2x,2x+1} for XCD x
#define BLKS_PER_XCD 134       // ceil(2000/15)
#define PPB_F 15

typedef float f32x4 __attribute__((ext_vector_type(4)));

#define TOP2(v) do { const float _v = (v); \
    if (_v > m1) { m2 = m1; m1 = _v; } else if (_v > m2) { m2 = _v; } } while (0)

// ------- A: feat[B,C,H,W] -> featM[B,H*W,16] (64B rows) + featC[B,H*W] --------
__global__ __launch_bounds__(256) void transpose_feat(
    const float* __restrict__ feat,
    float* __restrict__ featM,
    float* __restrict__ featC)
{
    __shared__ float s[NC][257];
    const int bid = blockIdx.x;                     // 4096 (div by 8)
    const int l   = ((bid & 7) << 9) | (bid >> 3);  // XCD x -> batches {2x,2x+1}
    const int b   = l >> 8;
    const int hw0 = (l & 255) << 8;
    const int tid = threadIdx.x;
    const float* fb = feat + (size_t)b * NC * (NH * NW) + hw0;
    #pragma unroll
    for (int c = 0; c < NC; ++c)
        s[c][tid] = fb[c * (NH * NW) + tid];
    __syncthreads();
    float4* outp = reinterpret_cast<float4*>(
        featM + ((size_t)b * (NH * NW) + hw0) * 16);
    #pragma unroll
    for (int i = tid; i < 256 * 4; i += 256) {      // 4 float4 per position
        const int p = i >> 2;
        const int c = (i & 3) * 4;
        outp[i] = make_float4(s[c][p], s[c + 1][p], s[c + 2][p], s[c + 3][p]);
    }
    featC[(size_t)b * (NH * NW) + hw0 + tid] = s[16][tid];
}

// ------- B: fused sample + top2 + MLP (round-2 structure, 16+1 gather) --------
__global__ __launch_bounds__(256) void lqe_fused_t(
    const float* __restrict__ scores,
    const float* __restrict__ pred_poses,
    const float* __restrict__ featM,
    const float* __restrict__ featC,
    const float* __restrict__ w1,
    const float* __restrict__ b1,
    const float* __restrict__ w2,
    const float* __restrict__ b2,
    float* __restrict__ out)
{
    __shared__ float s_w1[HID * IN_DIM];
    __shared__ float s_b1[HID];
    __shared__ float s_w2[HID];
    __shared__ float s_x[PPB][IN_DIM + 1];

    const int tid    = threadIdx.x;
    const int xcd    = blockIdx.x & 7;
    const int idx    = blockIdx.x >> 3;             // 0..133
    const int local0 = idx * PPB;

    for (int i = tid; i < HID * IN_DIM; i += 256) s_w1[i] = w1[i];
    if (tid < HID) { s_b1[tid] = b1[tid]; s_w2[tid] = w2[tid]; }

    if (tid < PPB * NK) {
        const int lp = tid / NK;
        const int k  = tid - lp * NK;
        const int local = local0 + lp;
        if (local < PAIRS_PER_XCD) {
            const int pair = xcd * PAIRS_PER_XCD + local;
            const int b = pair / NL;
            const float2 p = *reinterpret_cast<const float2*>(
                pred_poses + (size_t)pair * (2 * NK) + 2 * k);
            const float gx = 2.0f * p.x - 1.0f;
            const float gy = 2.0f * p.y - 1.0f;
            const float fx = (gx + 1.0f) * (0.5f * NW) - 0.5f;
            const float fy = (gy + 1.0f) * (0.5f * NH) - 0.5f;
            const float x0f = floorf(fx), y0f = floorf(fy);
            const float wx = fx - x0f,   wy = fy - y0f;
            const int ix0 = (int)x0f, iy0 = (int)y0f;
            const int ix1 = ix0 + 1,  iy1 = iy0 + 1;
            const float vx0 = (ix0 >= 0 && ix0 < NW) ? 1.f : 0.f;
            const float vx1 = (ix1 >= 0 && ix1 < NW) ? 1.f : 0.f;
            const float vy0 = (iy0 >= 0 && iy0 < NH) ? 1.f : 0.f;
            const float vy1 = (iy1 >= 0 && iy1 < NH) ? 1.f : 0.f;
            const float w00 = (1.f - wx) * (1.f - wy) * vx0 * vy0;
            const float w10 = wx * (1.f - wy) * vx1 * vy0;
            const float w01 = (1.f - wx) * wy * vx0 * vy1;
            const float w11 = wx * wy * vx1 * vy1;
            const int cx0 = min(max(ix0, 0), NW - 1), cx1 = min(max(ix1, 0), NW - 1);
            const int cy0 = min(max(iy0, 0), NH - 1), cy1 = min(max(iy1, 0), NH - 1);
            const int o00 = cy0 * NW + cx0, o10 = cy0 * NW + cx1;
            const int o01 = cy1 * NW + cx0, o11 = cy1 * NW + cx1;
            const float* fm = featM + (size_t)b * (NH * NW) * 16;
            const float* fc = featC + (size_t)b * (NH * NW);
            const float* pm00 = fm + (size_t)o00 * 16;
            const float* pm10 = fm + (size_t)o10 * 16;
            const float* pm01 = fm + (size_t)o01 * 16;
            const float* pm11 = fm + (size_t)o11 * 16;

            // first 16B of each corner line: 4 independent line-misses in flight
            const f32x4 A0 = *(const f32x4*)(pm00);
            const f32x4 B0 = *(const f32x4*)(pm10);
            const f32x4 C0 = *(const f32x4*)(pm01);
            const f32x4 D0 = *(const f32x4*)(pm11);
            // channel-16 plane (L2-resident per XCD)
            const float e00 = fc[o00], e10 = fc[o10];
            const float e01 = fc[o01], e11 = fc[o11];
            // remaining 48B of each line: L1 hits
            const f32x4 A1 = *(const f32x4*)(pm00 + 4);
            const f32x4 B1 = *(const f32x4*)(pm10 + 4);
            const f32x4 C1 = *(const f32x4*)(pm01 + 4);
            const f32x4 D1 = *(const f32x4*)(pm11 + 4);
            const f32x4 A2 = *(const f32x4*)(pm00 + 8);
            const f32x4 B2 = *(const f32x4*)(pm10 + 8);
            const f32x4 C2 = *(const f32x4*)(pm01 + 8);
            const f32x4 D2 = *(const f32x4*)(pm11 + 8);
            const f32x4 A3 = *(const f32x4*)(pm00 + 12);
            const f32x4 B3 = *(const f32x4*)(pm10 + 12);
            const f32x4 C3 = *(const f32x4*)(pm01 + 12);
            const f32x4 D3 = *(const f32x4*)(pm11 + 12);

            float m1 = -INFINITY, m2 = -INFINITY;
            #pragma unroll
            for (int e = 0; e < 4; ++e)
                TOP2(w00 * A0[e] + w10 * B0[e] + w01 * C0[e] + w11 * D0[e]);
            #pragma unroll
            for (int e = 0; e < 4; ++e)
                TOP2(w00 * A1[e] + w10 * B1[e] + w01 * C1[e] + w11 * D1[e]);
            #pragma unroll
            for (int e = 0; e < 4; ++e)
                TOP2(w00 * A2[e] + w10 * B2[e] + w01 * C2[e] + w11 * D2[e]);
            #pragma unroll
            for (int e = 0; e < 4; ++e)
                TOP2(w00 * A3[e] + w10 * B3[e] + w01 * C3[e] + w11 * D3[e]);
            TOP2(w00 * e00 + w10 * e10 + w01 * e01 + w11 * e11);

            s_x[lp][3 * k + 0] = m1;
            s_x[lp][3 * k + 1] = m2;
            s_x[lp][3 * k + 2] = 0.5f * (m1 + m2);
        }
    }
    __syncthreads();

    const int wv = tid >> 6;
    const int lane = tid & 63;
    const float vb2 = b2[0];
    for (int lp = wv; lp < PPB; lp += 4) {
        if (local0 + lp >= PAIRS_PER_XCD) break;     // wave-uniform exit
        const int pair = xcd * PAIRS_PER_XCD + local0 + lp;
        float h = s_b1[lane];
        #pragma unroll
        for (int i = 0; i < IN_DIM; ++i)
            h = fmaf(s_x[lp][i], s_w1[lane * IN_DIM + i], h);
        h = fmaxf(h, 0.f);
        float pval = h * s_w2[lane];
        #pragma unroll
        for (int off = 32; off >= 1; off >>= 1)
            pval += __shfl_xor(pval, off, 64);
        if (lane == 0) out[pair] = scores[pair] + pval + vb2;
    }
}

// ---------------- fallback (round-1 verified): direct gather -------------------
__global__ __launch_bounds__(256) void lqe_fused_direct(
    const float* __restrict__ scores,
    const float* __restrict__ pred_poses,
    const float* __restrict__ feat,
    const float* __restrict__ w1,
    const float* __restrict__ b1,
    const float* __restrict__ w2,
    const float* __restrict__ b2,
    float* __restrict__ out)
{
    __shared__ float s_w1[HID * IN_DIM];
    __shared__ float s_b1[HID];
    __shared__ float s_w2[HID];
    __shared__ float s_x[PPB_F][IN_DIM + 1];

    const int tid = threadIdx.x;
    for (int i = tid; i < HID * IN_DIM; i += 256) s_w1[i] = w1[i];
    if (tid < HID) { s_b1[tid] = b1[tid]; s_w2[tid] = w2[tid]; }

    if (tid < PPB_F * NK) {
        const int lp = tid / NK;
        const int k  = tid - lp * NK;
        const int pair = blockIdx.x * PPB_F + lp;
        if (pair < NPAIR) {
            const int b = pair / NL;
            const float2 p = *reinterpret_cast<const float2*>(
                pred_poses + (size_t)pair * (2 * NK) + 2 * k);
            const float gx = 2.0f * p.x - 1.0f;
            const float gy = 2.0f * p.y - 1.0f;
            const float fx = (gx + 1.0f) * (0.5f * NW) - 0.5f;
            const float fy = (gy + 1.0f) * (0.5f * NH) - 0.5f;
            const float x0f = floorf(fx), y0f = floorf(fy);
            const float wx = fx - x0f,   wy = fy - y0f;
            const int ix0 = (int)x0f, iy0 = (int)y0f;
            const int ix1 = ix0 + 1,  iy1 = iy0 + 1;
            const float vx0 = (ix0 >= 0 && ix0 < NW) ? 1.f : 0.f;
            const float vx1 = (ix1 >= 0 && ix1 < NW) ? 1.f : 0.f;
            const float vy0 = (iy0 >= 0 && iy0 < NH) ? 1.f : 0.f;
            const float vy1 = (iy1 >= 0 && iy1 < NH) ? 1.f : 0.f;
            const float w00 = (1.f - wx) * (1.f - wy) * vx0 * vy0;
            const float w10 = wx * (1.f - wy) * vx1 * vy0;
            const float w01 = (1.f - wx) * wy * vx0 * vy1;
            const float w11 = wx * wy * vx1 * vy1;
            const int cx0 = min(max(ix0, 0), NW - 1), cx1 = min(max(ix1, 0), NW - 1);
            const int cy0 = min(max(iy0, 0), NH - 1), cy1 = min(max(iy1, 0), NH - 1);
            const int o00 = cy0 * NW + cx0, o10 = cy0 * NW + cx1;
            const int o01 = cy1 * NW + cx0, o11 = cy1 * NW + cx1;
            const float* fb = feat + (size_t)b * NC * NH * NW;
            float m1 = -INFINITY, m2 = -INFINITY;
            #pragma unroll
            for (int c = 0; c < NC; ++c) {
                const float* fcp = fb + c * (NH * NW);
                TOP2(w00 * fcp[o00] + w10 * fcp[o10] + w01 * fcp[o01] + w11 * fcp[o11]);
            }
            s_x[lp][3 * k + 0] = m1;
            s_x[lp][3 * k + 1] = m2;
            s_x[lp][3 * k + 2] = 0.5f * (m1 + m2);
        }
    }
    __syncthreads();

    const int wv = tid >> 6;
    const int lane = tid & 63;
    const float vb2 = b2[0];
    for (int lp = wv; lp < PPB_F; lp += 4) {
        const int pair = blockIdx.x * PPB_F + lp;
        if (pair >= NPAIR) break;
        float h = s_b1[lane];
        #pragma unroll
        for (int i = 0; i < IN_DIM; ++i)
            h = fmaf(s_x[lp][i], s_w1[lane * IN_DIM + i], h);
        h = fmaxf(h, 0.f);
        float pval = h * s_w2[lane];
        #pragma unroll
        for (int off = 32; off >= 1; off >>= 1)
            pval += __shfl_xor(pval, off, 64);
        if (lane == 0) out[pair] = scores[pair] + pval + vb2;
    }
}

extern "C" void kernel_launch(void* const* d_in, const int* in_sizes, int n_in,
                              void* d_out, int out_size, void* d_ws, size_t ws_size,
                              hipStream_t stream) {
    const float* scores     = (const float*)d_in[0];
    const float* pred_poses = (const float*)d_in[1];
    const float* feat       = (const float*)d_in[2];
    const float* w1         = (const float*)d_in[3];
    const float* b1         = (const float*)d_in[4];
    const float* w2         = (const float*)d_in[5];
    const float* b2         = (const float*)d_in[6];
    float* out = (float*)d_out;

    const size_t bytesM = (size_t)NB * NH * NW * 16 * sizeof(float);  // 64 MB
    const size_t bytesC = (size_t)NB * NH * NW * sizeof(float);       // 4 MB

    if (ws_size >= bytesM + bytesC) {
        float* featM = (float*)d_ws;
        float* featC = (float*)((char*)d_ws + bytesM);
        transpose_feat<<<NB * 256, 256, 0, stream>>>(feat, featM, featC);
        lqe_fused_t<<<8 * BLKS_PER_XCD, 256, 0, stream>>>(
            scores, pred_poses, featM, featC, w1, b1, w2, b2, out);
    } else {
        const int grid = (NPAIR + PPB_F - 1) / PPB_F;
        lqe_fused_direct<<<grid, 256, 0, stream>>>(scores, pred_poses, feat,
                                                   w1, b1, w2, b2, out);
    }
}